// Round 16
// baseline (350.723 us; speedup 1.0000x reference)
//
#include <hip/hip_runtime.h>
#include <hip/hip_bf16.h>

#define T_LEN 256
#define B_SZ  256
#define EMB   128
#define UNITS 100
#define GATES 400           // 4*UNITS
#define NCOL  800           // [fwd 400 | bwd 400], j = gate*100+unit within dir
#define NQ    52            // f16 k-pairs (104 padded k)

typedef __attribute__((ext_vector_type(8))) short short8v;
typedef __attribute__((ext_vector_type(4))) short short4v;
typedef __attribute__((ext_vector_type(4))) float f32x4;
typedef _Float16 half2v __attribute__((ext_vector_type(2)));

static __device__ __forceinline__ float bf2f(short s) {
    unsigned u = ((unsigned)(unsigned short)s) << 16;
    return __builtin_bit_cast(float, u);
}
static __device__ __forceinline__ short f2bf(float f) {
    return __builtin_bit_cast(short, __float2bfloat16(f));
}
static __device__ __forceinline__ float fast_sigmoid(float x) {
    return 1.f / (1.f + __expf(-x));
}
static __device__ __forceinline__ float fast_tanh(float x) {
    return 1.f - 2.f / (1.f + __expf(2.f * x));
}
static __device__ __forceinline__ float fdot2p(unsigned hp, unsigned up, float c) {
#if __has_builtin(__builtin_amdgcn_fdot2)
    return __builtin_amdgcn_fdot2(__builtin_bit_cast(half2v, hp),
                                  __builtin_bit_cast(half2v, up), c, false);
#else
    const half2v a = __builtin_bit_cast(half2v, hp);
    const half2v b = __builtin_bit_cast(half2v, up);
    return fmaf((float)a[1], (float)b[1], fmaf((float)a[0], (float)b[0], c));
#endif
}

// ---------------------------------------------------------------------------
// prep: (a) WbT bf16 transposed word-part weights (c = dir*400+j, k-major 128)
//       (b) P_pos/P_dep tables (dep absorbs bias)
//       (c) Upk[dir][q][col]: f16 pair (U[2q][col], U[2q+1][col]), q<52
//       (d) bf16 MFMA layout probe -> flag[0]
// ---------------------------------------------------------------------------
#define PREP_WT_BLOCKS 100
#define PREP_TAB_BLOCKS 107
#define PREP_UPK_BLOCKS 21

__global__ __launch_bounds__(256) void prep(
    const float* __restrict__ Wf, const float* __restrict__ Wb,
    const float* __restrict__ bf_, const float* __restrict__ bb_,
    const float* __restrict__ Ep, const float* __restrict__ Ed,
    const float* __restrict__ Uf, const float* __restrict__ Ub,
    __hip_bfloat16* __restrict__ WbT, float* __restrict__ Ppos,
    float* __restrict__ Pdep, unsigned* __restrict__ Upk, int* __restrict__ flag)
{
    __shared__ short Ap[16 * 32];
    __shared__ short Bp[32 * 16];

    const int bx = blockIdx.x, tid = threadIdx.x;

    if (bx < PREP_WT_BLOCKS) {
        const int base = bx * 1024 + tid * 4;
#pragma unroll
        for (int q = 0; q < 4; ++q) {
            const int id = base + q;            // id = c*128 + k
            const int c = id >> 7, k = id & 127;
            const int dir = c >= GATES;
            const int j = c - dir * GATES;
            const float* W = dir ? Wb : Wf;
            WbT[id] = __float2bfloat16(W[k * GATES + j]);
        }
    } else if (bx < PREP_WT_BLOCKS + PREP_TAB_BLOCKS) {
        const int p = bx - PREP_WT_BLOCKS;
        const bool isPos = p < 53;
        const float* Erow = isPos ? (Ep + p * EMB) : (Ed + (size_t)(p - 53) * EMB);
        const int rowoff = isPos ? EMB : 2 * EMB;
        float* dst = isPos ? (Ppos + (size_t)p * NCOL) : (Pdep + (size_t)(p - 53) * NCOL);
        for (int c = tid; c < NCOL; c += 256) {
            const int dir = c >= GATES;
            const int j = c - dir * GATES;
            const float* W = dir ? Wb : Wf;
            float s = 0.f;
            for (int k = 0; k < EMB; ++k)
                s = fmaf(Erow[k], W[(size_t)(rowoff + k) * GATES + j], s);
            if (!isPos) s += (dir ? bb_[j] : bf_[j]);
            dst[c] = s;
        }
    } else if (bx < PREP_WT_BLOCKS + PREP_TAB_BLOCKS + PREP_UPK_BLOCKS) {
        const int p2 = bx - PREP_WT_BLOCKS - PREP_TAB_BLOCKS;
#pragma unroll
        for (int i = 0; i < 8; ++i) {
            const int e = p2 * 2048 + tid * 8 + i;     // e = dir*20800 + q*400 + col
            if (e < 2 * NQ * GATES) {
                const int dir = e / (NQ * GATES);
                const int rem = e - dir * (NQ * GATES);
                const int q = rem / GATES, col = rem - q * GATES;
                const float* U = dir ? Ub : Uf;
                const int k0 = 2 * q, k1 = 2 * q + 1;
                const float v0 = (k0 < UNITS) ? U[(size_t)k0 * GATES + col] : 0.f;
                const float v1 = (k1 < UNITS) ? U[(size_t)k1 * GATES + col] : 0.f;
                const unsigned lo = (unsigned)(unsigned short)__builtin_bit_cast(short, (_Float16)v0);
                const unsigned hi = (unsigned)(unsigned short)__builtin_bit_cast(short, (_Float16)v1);
                Upk[e] = lo | (hi << 16);
            }
        }
    } else {
        // ---- bf16 MFMA layout probe ----
        if (tid < 64) {
            for (int e = tid; e < 512; e += 64) {
                const int m = e >> 5, k = e & 31;
                Ap[e] = f2bf((float)((m * 3 + k * 5) % 7 - 3));
            }
            for (int e = tid; e < 512; e += 64) {
                const int k = e >> 4, n = e & 15;
                Bp[e] = f2bf((float)((k * 7 + n * 3) % 5 - 2));
            }
        }
        __syncthreads();
        if (tid < 64) {
            const int l = tid, mn = l & 15, grp = l >> 4;
            float ref[4];
#pragma unroll
            for (int i = 0; i < 4; ++i) {
                const int m = grp * 4 + i;
                float s = 0.f;
                for (int k = 0; k < 32; ++k)
                    s += bf2f(Ap[m * 32 + k]) * bf2f(Bp[k * 16 + mn]);
                ref[i] = s;
            }
            short8v a8, b8;
#pragma unroll
            for (int e = 0; e < 8; ++e) {
                const int k8 = grp * 8 + e;
                a8[e] = Ap[mn * 32 + k8];
                b8[e] = Bp[k8 * 16 + mn];
            }
            f32x4 z = {0.f, 0.f, 0.f, 0.f};
            f32x4 d8 = __builtin_amdgcn_mfma_f32_16x16x32_bf16(a8, b8, z, 0, 0, 0);
            const bool ok8 = (d8[0] == ref[0]) && (d8[1] == ref[1]) &&
                             (d8[2] == ref[2]) && (d8[3] == ref[3]);
            const unsigned long long m8 = __ballot(ok8);
            if (tid == 0) flag[0] = (m8 == ~0ULL) ? 0 : 1;
        }
    }
}

// ---------------------------------------------------------------------------
// embed_gemm: xw[r][c] bf16, r = t*256+b, c = dir*400 + gate*100 + unit
// (round-3 proven structure)
// ---------------------------------------------------------------------------
#define MT 64
#define NT 160

__global__ __launch_bounds__(256) void embed_gemm(
    const int* __restrict__ words, const int* __restrict__ pos, const int* __restrict__ dep,
    const float* __restrict__ Ew, const __hip_bfloat16* __restrict__ WbT,
    const float* __restrict__ Ppos, const float* __restrict__ Pdep,
    const int* __restrict__ flag, __hip_bfloat16* __restrict__ xw)
{
    __shared__ __align__(16) short As[MT * 128];
    __shared__ __align__(16) short Bs[NT * 128];
    __shared__ int widx[MT], pidx[MT], didx[MT];

    const int tid = threadIdx.x;
    const int bx = blockIdx.x, by = blockIdx.y;
    const int r0 = bx * MT;
    const int t = r0 >> 8, b0 = r0 & 255;
    const int n0 = by * NT;

    if (tid < MT)             widx[tid]          = words[(size_t)(b0 + tid) * T_LEN + t];
    else if (tid < 2 * MT)    pidx[tid - MT]     = pos[(size_t)(b0 + tid - MT) * T_LEN + t];
    else if (tid < 3 * MT)    didx[tid - 2 * MT] = dep[(size_t)(b0 + tid - 2 * MT) * T_LEN + t];
    __syncthreads();

#pragma unroll
    for (int q = 0; q < 4; ++q) {
        const int ch = tid + q * 256;
        const int row = ch >> 4, c16 = ch & 15;
        const float* src = Ew + (size_t)widx[row] * EMB + c16 * 8;
        const float4 v0 = *reinterpret_cast<const float4*>(src);
        const float4 v1 = *reinterpret_cast<const float4*>(src + 4);
        short8v pk;
        pk[0] = f2bf(v0.x); pk[1] = f2bf(v0.y); pk[2] = f2bf(v0.z); pk[3] = f2bf(v0.w);
        pk[4] = f2bf(v1.x); pk[5] = f2bf(v1.y); pk[6] = f2bf(v1.z); pk[7] = f2bf(v1.w);
        *reinterpret_cast<short8v*>(&As[row * 128 + ((c16 ^ (row & 7)) << 3)]) = pk;
    }
#pragma unroll
    for (int q = 0; q < 10; ++q) {
        const int ch = tid + q * 256;
        const int col = ch >> 4, c16 = ch & 15;
        const short* src = reinterpret_cast<const short*>(WbT) + (size_t)(n0 + col) * 128 + c16 * 8;
        const short8v v = *reinterpret_cast<const short8v*>(src);
        *reinterpret_cast<short8v*>(&Bs[col * 128 + ((c16 ^ (col & 7)) << 3)]) = v;
    }
    __syncthreads();

    const int w = tid >> 6, l = tid & 63;
    const int lr = l & 15, lg = l >> 4;
    const int arow = w * 16 + lr;

    f32x4 acc[10];
#pragma unroll
    for (int ni = 0; ni < 10; ++ni) acc[ni] = f32x4{0.f, 0.f, 0.f, 0.f};

    const int lay = flag[0];

    if (lay == 0) {
#pragma unroll
        for (int kk = 0; kk < 4; ++kk) {
            const int c16 = kk * 4 + lg;
            const short8v a = *reinterpret_cast<const short8v*>(
                &As[arow * 128 + ((c16 ^ (arow & 7)) << 3)]);
#pragma unroll
            for (int ni = 0; ni < 10; ++ni) {
                const int col = ni * 16 + lr;
                const short8v bfr = *reinterpret_cast<const short8v*>(
                    &Bs[col * 128 + ((c16 ^ (col & 7)) << 3)]);
                acc[ni] = __builtin_amdgcn_mfma_f32_16x16x32_bf16(a, bfr, acc[ni], 0, 0, 0);
            }
        }
    } else {
#pragma unroll
        for (int kk = 0; kk < 4; ++kk) {
            const int ch16 = kk * 4 + (lg >> 1);
            const int inner = (lg & 1) * 4;
            const int alo_i = arow * 128 + ((ch16 ^ (arow & 7)) << 3) + inner;
            const int ahi_i = arow * 128 + (((ch16 + 2) ^ (arow & 7)) << 3) + inner;
            const short4v alo = *reinterpret_cast<const short4v*>(&As[alo_i]);
            const short4v ahi = *reinterpret_cast<const short4v*>(&As[ahi_i]);
            short8v a;
            a[0] = alo[0]; a[1] = alo[1]; a[2] = alo[2]; a[3] = alo[3];
            a[4] = ahi[0]; a[5] = ahi[1]; a[6] = ahi[2]; a[7] = ahi[3];
#pragma unroll
            for (int ni = 0; ni < 10; ++ni) {
                const int col = ni * 16 + lr;
                const int blo_i = col * 128 + ((ch16 ^ (col & 7)) << 3) + inner;
                const int bhi_i = col * 128 + (((ch16 + 2) ^ (col & 7)) << 3) + inner;
                const short4v blo = *reinterpret_cast<const short4v*>(&Bs[blo_i]);
                const short4v bhi = *reinterpret_cast<const short4v*>(&Bs[bhi_i]);
                short8v b;
                b[0] = blo[0]; b[1] = blo[1]; b[2] = blo[2]; b[3] = blo[3];
                b[4] = bhi[0]; b[5] = bhi[1]; b[6] = bhi[2]; b[7] = bhi[3];
                acc[ni] = __builtin_amdgcn_mfma_f32_16x16x32_bf16(a, b, acc[ni], 0, 0, 0);
            }
        }
    }

    const int rbase = w * 16 + lg * 4;
    int pix[4], dix[4];
#pragma unroll
    for (int i = 0; i < 4; ++i) { pix[i] = pidx[rbase + i]; dix[i] = didx[rbase + i]; }
#pragma unroll
    for (int ni = 0; ni < 10; ++ni) {
        const int c = n0 + ni * 16 + lr;
#pragma unroll
        for (int i = 0; i < 4; ++i) {
            const float v = acc[ni][i]
                          + Ppos[(size_t)pix[i] * NCOL + c]
                          + Pdep[(size_t)dix[i] * NCOL + c];
            xw[(size_t)(r0 + rbase + i) * NCOL + c] = __float2bfloat16(v);
        }
    }
}

// ---------------------------------------------------------------------------
// lstm_valu: one block per (b, dir) chain -> 512 blocks, 2 co-resident/CU.
// r10/r11 proven-best structure. ONLY change vs r15: __launch_bounds__(512,2)
// — declares 2 waves/EU occupancy target (= current 16 waves/CU), raising the
// arch-VGPR budget so upk[52] (currently in AGPRs at VGPR_Count=40, paying
// accvgpr moves on the dot path) can be allocated in arch VGPRs (~92 needed,
// within the 65-128 band that still allows 16 waves/CU per m69).
// ---------------------------------------------------------------------------
#define BAR() do { \
    asm volatile("s_waitcnt lgkmcnt(0)" ::: "memory"); \
    __builtin_amdgcn_sched_barrier(0); \
    __builtin_amdgcn_s_barrier(); \
    __builtin_amdgcn_sched_barrier(0); \
} while (0)

__global__ __launch_bounds__(512, 2) void lstm_valu(
    const int* __restrict__ words,
    const __hip_bfloat16* __restrict__ xw,
    const unsigned* __restrict__ Upk,
    _Float16* __restrict__ h_f, _Float16* __restrict__ h_b)
{
    const int b = blockIdx.x >> 1, dirv = blockIdx.x & 1;
    _Float16* hout = dirv ? h_b : h_f;
    const int coff = dirv * GATES;
    const unsigned* up = Upk + (size_t)dirv * NQ * GATES;

    __shared__ __align__(16) _Float16 h_sh[104];
    __shared__ float z_sh[GATES];
    __shared__ unsigned char m_sh[T_LEN];

    const int tid = threadIdx.x;
    const bool isCol = tid < GATES;
    const int colid = isCol ? tid : (GATES - 1);

    for (int i = tid; i < T_LEN; i += 512)
        m_sh[i] = (unsigned char)(words[(size_t)b * T_LEN + i] != 0);
    if (tid < 52) reinterpret_cast<unsigned*>(h_sh)[tid] = 0u;   // all 104 f16

    unsigned upk[NQ];
#pragma unroll
    for (int q = 0; q < NQ; ++q) upk[q] = up[q * GATES + colid];
#pragma unroll
    for (int q = 0; q < NQ; ++q) asm volatile("" : "+v"(upk[q]));

    float c = 0.f, h = 0.f;
    __syncthreads();

    const int t0 = dirv ? (T_LEN - 1) : 0;
    const int dt = dirv ? -1 : 1;
    const short* xs = reinterpret_cast<const short*>(xw);

    short pf = 0;
    if (isCol) pf = xs[((size_t)t0 * B_SZ + b) * NCOL + coff + tid];

    for (int s = 0; s < T_LEN; ++s) {
        const int t = t0 + dt * s;
        int tn = t + dt; tn = tn < 0 ? 0 : (tn > T_LEN - 1 ? T_LEN - 1 : tn);

        short pfn = pf;
        if (isCol) {
            const float zx = bf2f(pf);
            pfn = xs[((size_t)tn * B_SZ + b) * NCOL + coff + tid];   // prefetch
            float a0 = 0.f, a1 = 0.f, a2 = 0.f, a3 = 0.f;
            const uint4* h4 = reinterpret_cast<const uint4*>(h_sh);
#pragma unroll
            for (int qq = 0; qq < 13; ++qq) {
                const uint4 hv = h4[qq];
                a0 = fdot2p(hv.x, upk[4 * qq + 0], a0);
                a1 = fdot2p(hv.y, upk[4 * qq + 1], a1);
                a2 = fdot2p(hv.z, upk[4 * qq + 2], a2);
                a3 = fdot2p(hv.w, upk[4 * qq + 3], a3);
            }
            z_sh[tid] = zx + (a0 + a1) + (a2 + a3);
        }
        pf = pfn;

        BAR();

        if (tid < UNITS) {
            const float zi = z_sh[tid];
            const float zf = z_sh[tid + UNITS];
            const float zg = z_sh[tid + 2 * UNITS];
            const float zo = z_sh[tid + 3 * UNITS];
            const float ig = fast_sigmoid(zi);
            const float fg = fast_sigmoid(zf);
            const float gg = fast_tanh(zg);
            const float og = fast_sigmoid(zo);
            const float cn = fg * c + ig * gg;
            const float hn = og * fast_tanh(cn);
            const bool  m  = m_sh[t] != 0;
            h = m ? hn : h;
            c = m ? cn : c;
            const _Float16 hh = (_Float16)h;
            h_sh[tid] = hh;
            hout[((size_t)t * B_SZ + b) * UNITS + tid] = hh;
        }

        BAR();
    }
}

// ---------------------------------------------------------------------------
// out_proj: out[b][t] = sigmoid(h_f . Wo[0:100] + h_b . Wo[100:200] + bo)
// ---------------------------------------------------------------------------
__global__ __launch_bounds__(256) void out_proj(
    const _Float16* __restrict__ h_f, const _Float16* __restrict__ h_b,
    const float* __restrict__ Wo, const float* __restrict__ bo,
    float* __restrict__ out)
{
    const int tid = threadIdx.x;
    const int g = tid >> 2, sub = tid & 3;
    const int r = blockIdx.x * 64 + g;      // r = t*256 + b
    const int t = r >> 8, b = r & 255;

    const _Float16* hf = h_f + (size_t)r * UNITS;
    const _Float16* hb = h_b + (size_t)r * UNITS;

    float s = 0.f;
    const int k0 = sub * 25;
#pragma unroll
    for (int k = 0; k < 25; ++k) s = fmaf((float)hf[k0 + k], Wo[k0 + k], s);
#pragma unroll
    for (int k = 0; k < 25; ++k) s = fmaf((float)hb[k0 + k], Wo[UNITS + k0 + k], s);

    s += __shfl_xor(s, 1);
    s += __shfl_xor(s, 2);

    if (sub == 0)
        out[(size_t)b * T_LEN + t] = 1.f / (1.f + __expf(-(s + bo[0])));
}

// ---------------------------------------------------------------------------
extern "C" void kernel_launch(void* const* d_in, const int* in_sizes, int n_in,
                              void* d_out, int out_size, void* d_ws, size_t ws_size,
                              hipStream_t stream)
{
    const int*   words = (const int*)d_in[0];
    const int*   pos   = (const int*)d_in[1];
    const int*   dep   = (const int*)d_in[2];
    const float* Ew    = (const float*)d_in[3];
    const float* Ep    = (const float*)d_in[4];
    const float* Ed    = (const float*)d_in[5];
    const float* Wf    = (const float*)d_in[6];
    const float* Uf    = (const float*)d_in[7];
    const float* bf_   = (const float*)d_in[8];
    const float* Wb    = (const float*)d_in[9];
    const float* Ub    = (const float*)d_in[10];
    const float* bb_   = (const float*)d_in[11];
    const float* Wo    = (const float*)d_in[12];
    const float* bo    = (const float*)d_in[13];
    float* out = (float*)d_out;

    auto alignup = [](size_t x) { return (x + 255) & ~(size_t)255; };
    char* p = (char*)d_ws;
    __hip_bfloat16* xw = (__hip_bfloat16*)p;  p += alignup((size_t)T_LEN * B_SZ * NCOL * 2);
    _Float16* h_f = (_Float16*)p;             p += alignup((size_t)T_LEN * B_SZ * UNITS * 2);
    _Float16* h_b = (_Float16*)p;             p += alignup((size_t)T_LEN * B_SZ * UNITS * 2);
    __hip_bfloat16* WbT = (__hip_bfloat16*)p; p += alignup((size_t)NCOL * 128 * 2);
    float* Ppos = (float*)p;                  p += alignup((size_t)53 * NCOL * 4);
    float* Pdep = (float*)p;                  p += alignup((size_t)54 * NCOL * 4);
    unsigned* Upk = (unsigned*)p;             p += alignup((size_t)2 * NQ * GATES * 4);
    int* flag = (int*)p;

    prep<<<dim3(PREP_WT_BLOCKS + PREP_TAB_BLOCKS + PREP_UPK_BLOCKS + 1), 256, 0, stream>>>(
        Wf, Wb, bf_, bb_, Ep, Ed, Uf, Ub, WbT, Ppos, Pdep, Upk, flag);

    embed_gemm<<<dim3((T_LEN * B_SZ) / MT, NCOL / NT), 256, 0, stream>>>(
        words, pos, dep, Ew, WbT, Ppos, Pdep, flag, xw);

    lstm_valu<<<dim3(B_SZ * 2), 512, 0, stream>>>(words, xw, Upk, h_f, h_b);

    out_proj<<<dim3((T_LEN * B_SZ) / 64), 256, 0, stream>>>(h_f, h_b, Wo, bo, out);
}

// Round 17
// 347.541 us; speedup vs baseline: 1.0092x; 1.0092x over previous
//
#include <hip/hip_runtime.h>
#include <hip/hip_bf16.h>

#define T_LEN 256
#define B_SZ  256
#define EMB   128
#define UNITS 100
#define GATES 400           // 4*UNITS
#define NCOL  800           // [fwd 400 | bwd 400], j = gate*100+unit within dir
#define NQ    52            // f16 k-pairs (104 padded k)

typedef __attribute__((ext_vector_type(8))) short short8v;
typedef __attribute__((ext_vector_type(4))) short short4v;
typedef __attribute__((ext_vector_type(4))) float f32x4;
typedef _Float16 half2v __attribute__((ext_vector_type(2)));

static __device__ __forceinline__ float bf2f(short s) {
    unsigned u = ((unsigned)(unsigned short)s) << 16;
    return __builtin_bit_cast(float, u);
}
static __device__ __forceinline__ short f2bf(float f) {
    return __builtin_bit_cast(short, __float2bfloat16(f));
}
static __device__ __forceinline__ float fast_sigmoid(float x) {
    return 1.f / (1.f + __expf(-x));
}
static __device__ __forceinline__ float fast_tanh(float x) {
    return 1.f - 2.f / (1.f + __expf(2.f * x));
}
static __device__ __forceinline__ float fdot2p(unsigned hp, unsigned up, float c) {
#if __has_builtin(__builtin_amdgcn_fdot2)
    return __builtin_amdgcn_fdot2(__builtin_bit_cast(half2v, hp),
                                  __builtin_bit_cast(half2v, up), c, false);
#else
    const half2v a = __builtin_bit_cast(half2v, hp);
    const half2v b = __builtin_bit_cast(half2v, up);
    return fmaf((float)a[1], (float)b[1], fmaf((float)a[0], (float)b[0], c));
#endif
}

// ---------------------------------------------------------------------------
// prep: (a) WbT bf16 transposed word-part weights (c = dir*400+j, k-major 128)
//       (b) P_pos/P_dep tables (dep absorbs bias)
//       (c) Upk[dir][q][col]: f16 pair (U[2q][col], U[2q+1][col]), q<52
//       (d) bf16 MFMA layout probe -> flag[0]
// ---------------------------------------------------------------------------
#define PREP_WT_BLOCKS 100
#define PREP_TAB_BLOCKS 107
#define PREP_UPK_BLOCKS 21

__global__ __launch_bounds__(256) void prep(
    const float* __restrict__ Wf, const float* __restrict__ Wb,
    const float* __restrict__ bf_, const float* __restrict__ bb_,
    const float* __restrict__ Ep, const float* __restrict__ Ed,
    const float* __restrict__ Uf, const float* __restrict__ Ub,
    __hip_bfloat16* __restrict__ WbT, float* __restrict__ Ppos,
    float* __restrict__ Pdep, unsigned* __restrict__ Upk, int* __restrict__ flag)
{
    __shared__ short Ap[16 * 32];
    __shared__ short Bp[32 * 16];

    const int bx = blockIdx.x, tid = threadIdx.x;

    if (bx < PREP_WT_BLOCKS) {
        const int base = bx * 1024 + tid * 4;
#pragma unroll
        for (int q = 0; q < 4; ++q) {
            const int id = base + q;            // id = c*128 + k
            const int c = id >> 7, k = id & 127;
            const int dir = c >= GATES;
            const int j = c - dir * GATES;
            const float* W = dir ? Wb : Wf;
            WbT[id] = __float2bfloat16(W[k * GATES + j]);
        }
    } else if (bx < PREP_WT_BLOCKS + PREP_TAB_BLOCKS) {
        const int p = bx - PREP_WT_BLOCKS;
        const bool isPos = p < 53;
        const float* Erow = isPos ? (Ep + p * EMB) : (Ed + (size_t)(p - 53) * EMB);
        const int rowoff = isPos ? EMB : 2 * EMB;
        float* dst = isPos ? (Ppos + (size_t)p * NCOL) : (Pdep + (size_t)(p - 53) * NCOL);
        for (int c = tid; c < NCOL; c += 256) {
            const int dir = c >= GATES;
            const int j = c - dir * GATES;
            const float* W = dir ? Wb : Wf;
            float s = 0.f;
            for (int k = 0; k < EMB; ++k)
                s = fmaf(Erow[k], W[(size_t)(rowoff + k) * GATES + j], s);
            if (!isPos) s += (dir ? bb_[j] : bf_[j]);
            dst[c] = s;
        }
    } else if (bx < PREP_WT_BLOCKS + PREP_TAB_BLOCKS + PREP_UPK_BLOCKS) {
        const int p2 = bx - PREP_WT_BLOCKS - PREP_TAB_BLOCKS;
#pragma unroll
        for (int i = 0; i < 8; ++i) {
            const int e = p2 * 2048 + tid * 8 + i;     // e = dir*20800 + q*400 + col
            if (e < 2 * NQ * GATES) {
                const int dir = e / (NQ * GATES);
                const int rem = e - dir * (NQ * GATES);
                const int q = rem / GATES, col = rem - q * GATES;
                const float* U = dir ? Ub : Uf;
                const int k0 = 2 * q, k1 = 2 * q + 1;
                const float v0 = (k0 < UNITS) ? U[(size_t)k0 * GATES + col] : 0.f;
                const float v1 = (k1 < UNITS) ? U[(size_t)k1 * GATES + col] : 0.f;
                const unsigned lo = (unsigned)(unsigned short)__builtin_bit_cast(short, (_Float16)v0);
                const unsigned hi = (unsigned)(unsigned short)__builtin_bit_cast(short, (_Float16)v1);
                Upk[e] = lo | (hi << 16);
            }
        }
    } else {
        // ---- bf16 MFMA layout probe ----
        if (tid < 64) {
            for (int e = tid; e < 512; e += 64) {
                const int m = e >> 5, k = e & 31;
                Ap[e] = f2bf((float)((m * 3 + k * 5) % 7 - 3));
            }
            for (int e = tid; e < 512; e += 64) {
                const int k = e >> 4, n = e & 15;
                Bp[e] = f2bf((float)((k * 7 + n * 3) % 5 - 2));
            }
        }
        __syncthreads();
        if (tid < 64) {
            const int l = tid, mn = l & 15, grp = l >> 4;
            float ref[4];
#pragma unroll
            for (int i = 0; i < 4; ++i) {
                const int m = grp * 4 + i;
                float s = 0.f;
                for (int k = 0; k < 32; ++k)
                    s += bf2f(Ap[m * 32 + k]) * bf2f(Bp[k * 16 + mn]);
                ref[i] = s;
            }
            short8v a8, b8;
#pragma unroll
            for (int e = 0; e < 8; ++e) {
                const int k8 = grp * 8 + e;
                a8[e] = Ap[mn * 32 + k8];
                b8[e] = Bp[k8 * 16 + mn];
            }
            f32x4 z = {0.f, 0.f, 0.f, 0.f};
            f32x4 d8 = __builtin_amdgcn_mfma_f32_16x16x32_bf16(a8, b8, z, 0, 0, 0);
            const bool ok8 = (d8[0] == ref[0]) && (d8[1] == ref[1]) &&
                             (d8[2] == ref[2]) && (d8[3] == ref[3]);
            const unsigned long long m8 = __ballot(ok8);
            if (tid == 0) flag[0] = (m8 == ~0ULL) ? 0 : 1;
        }
    }
}

// ---------------------------------------------------------------------------
// embed_gemm: xw[r][c] bf16, r = t*256+b, c = dir*400 + gate*100 + unit
// (round-3 proven structure)
// ---------------------------------------------------------------------------
#define MT 64
#define NT 160

__global__ __launch_bounds__(256) void embed_gemm(
    const int* __restrict__ words, const int* __restrict__ pos, const int* __restrict__ dep,
    const float* __restrict__ Ew, const __hip_bfloat16* __restrict__ WbT,
    const float* __restrict__ Ppos, const float* __restrict__ Pdep,
    const int* __restrict__ flag, __hip_bfloat16* __restrict__ xw)
{
    __shared__ __align__(16) short As[MT * 128];
    __shared__ __align__(16) short Bs[NT * 128];
    __shared__ int widx[MT], pidx[MT], didx[MT];

    const int tid = threadIdx.x;
    const int bx = blockIdx.x, by = blockIdx.y;
    const int r0 = bx * MT;
    const int t = r0 >> 8, b0 = r0 & 255;
    const int n0 = by * NT;

    if (tid < MT)             widx[tid]          = words[(size_t)(b0 + tid) * T_LEN + t];
    else if (tid < 2 * MT)    pidx[tid - MT]     = pos[(size_t)(b0 + tid - MT) * T_LEN + t];
    else if (tid < 3 * MT)    didx[tid - 2 * MT] = dep[(size_t)(b0 + tid - 2 * MT) * T_LEN + t];
    __syncthreads();

#pragma unroll
    for (int q = 0; q < 4; ++q) {
        const int ch = tid + q * 256;
        const int row = ch >> 4, c16 = ch & 15;
        const float* src = Ew + (size_t)widx[row] * EMB + c16 * 8;
        const float4 v0 = *reinterpret_cast<const float4*>(src);
        const float4 v1 = *reinterpret_cast<const float4*>(src + 4);
        short8v pk;
        pk[0] = f2bf(v0.x); pk[1] = f2bf(v0.y); pk[2] = f2bf(v0.z); pk[3] = f2bf(v0.w);
        pk[4] = f2bf(v1.x); pk[5] = f2bf(v1.y); pk[6] = f2bf(v1.z); pk[7] = f2bf(v1.w);
        *reinterpret_cast<short8v*>(&As[row * 128 + ((c16 ^ (row & 7)) << 3)]) = pk;
    }
#pragma unroll
    for (int q = 0; q < 10; ++q) {
        const int ch = tid + q * 256;
        const int col = ch >> 4, c16 = ch & 15;
        const short* src = reinterpret_cast<const short*>(WbT) + (size_t)(n0 + col) * 128 + c16 * 8;
        const short8v v = *reinterpret_cast<const short8v*>(src);
        *reinterpret_cast<short8v*>(&Bs[col * 128 + ((c16 ^ (col & 7)) << 3)]) = v;
    }
    __syncthreads();

    const int w = tid >> 6, l = tid & 63;
    const int lr = l & 15, lg = l >> 4;
    const int arow = w * 16 + lr;

    f32x4 acc[10];
#pragma unroll
    for (int ni = 0; ni < 10; ++ni) acc[ni] = f32x4{0.f, 0.f, 0.f, 0.f};

    const int lay = flag[0];

    if (lay == 0) {
#pragma unroll
        for (int kk = 0; kk < 4; ++kk) {
            const int c16 = kk * 4 + lg;
            const short8v a = *reinterpret_cast<const short8v*>(
                &As[arow * 128 + ((c16 ^ (arow & 7)) << 3)]);
#pragma unroll
            for (int ni = 0; ni < 10; ++ni) {
                const int col = ni * 16 + lr;
                const short8v bfr = *reinterpret_cast<const short8v*>(
                    &Bs[col * 128 + ((c16 ^ (col & 7)) << 3)]);
                acc[ni] = __builtin_amdgcn_mfma_f32_16x16x32_bf16(a, bfr, acc[ni], 0, 0, 0);
            }
        }
    } else {
#pragma unroll
        for (int kk = 0; kk < 4; ++kk) {
            const int ch16 = kk * 4 + (lg >> 1);
            const int inner = (lg & 1) * 4;
            const int alo_i = arow * 128 + ((ch16 ^ (arow & 7)) << 3) + inner;
            const int ahi_i = arow * 128 + (((ch16 + 2) ^ (arow & 7)) << 3) + inner;
            const short4v alo = *reinterpret_cast<const short4v*>(&As[alo_i]);
            const short4v ahi = *reinterpret_cast<const short4v*>(&As[ahi_i]);
            short8v a;
            a[0] = alo[0]; a[1] = alo[1]; a[2] = alo[2]; a[3] = alo[3];
            a[4] = ahi[0]; a[5] = ahi[1]; a[6] = ahi[2]; a[7] = ahi[3];
#pragma unroll
            for (int ni = 0; ni < 10; ++ni) {
                const int col = ni * 16 + lr;
                const int blo_i = col * 128 + ((ch16 ^ (col & 7)) << 3) + inner;
                const int bhi_i = col * 128 + (((ch16 + 2) ^ (col & 7)) << 3) + inner;
                const short4v blo = *reinterpret_cast<const short4v*>(&Bs[blo_i]);
                const short4v bhi = *reinterpret_cast<const short4v*>(&Bs[bhi_i]);
                short8v b;
                b[0] = blo[0]; b[1] = blo[1]; b[2] = blo[2]; b[3] = blo[3];
                b[4] = bhi[0]; b[5] = bhi[1]; b[6] = bhi[2]; b[7] = bhi[3];
                acc[ni] = __builtin_amdgcn_mfma_f32_16x16x32_bf16(a, b, acc[ni], 0, 0, 0);
            }
        }
    }

    const int rbase = w * 16 + lg * 4;
    int pix[4], dix[4];
#pragma unroll
    for (int i = 0; i < 4; ++i) { pix[i] = pidx[rbase + i]; dix[i] = didx[rbase + i]; }
#pragma unroll
    for (int ni = 0; ni < 10; ++ni) {
        const int c = n0 + ni * 16 + lr;
#pragma unroll
        for (int i = 0; i < 4; ++i) {
            const float v = acc[ni][i]
                          + Ppos[(size_t)pix[i] * NCOL + c]
                          + Pdep[(size_t)dix[i] * NCOL + c];
            xw[(size_t)(r0 + rbase + i) * NCOL + c] = __float2bfloat16(v);
        }
    }
}

// ---------------------------------------------------------------------------
// lstm_valu: r10/r11/r15 proven-best structure + masked-step skipping.
// The pad mask is a suffix (words drawn from randint(1,..) then zeroed for
// t>=length), so: fwd computes t in [0,len) then bulk-writes carried h for
// the tail; bwd bulk-writes zeros for t in [len,256) and starts at t=len-1.
// Thread 0 finds len = first masked index AND verifies the suffix property;
// if it ever fails, len:=256 and this degenerates to the exact r15 loop.
// Mean len = 192 -> ~25% of steps skipped.
// ---------------------------------------------------------------------------
#define BAR() do { \
    asm volatile("s_waitcnt lgkmcnt(0)" ::: "memory"); \
    __builtin_amdgcn_sched_barrier(0); \
    __builtin_amdgcn_s_barrier(); \
    __builtin_amdgcn_sched_barrier(0); \
} while (0)

__global__ __launch_bounds__(512, 1) void lstm_valu(
    const int* __restrict__ words,
    const __hip_bfloat16* __restrict__ xw,
    const unsigned* __restrict__ Upk,
    _Float16* __restrict__ h_f, _Float16* __restrict__ h_b)
{
    const int b = blockIdx.x >> 1, dirv = blockIdx.x & 1;
    _Float16* hout = dirv ? h_b : h_f;
    const int coff = dirv * GATES;
    const unsigned* up = Upk + (size_t)dirv * NQ * GATES;

    __shared__ __align__(16) _Float16 h_sh[104];
    __shared__ float z_sh[GATES];
    __shared__ unsigned char m_sh[T_LEN];
    __shared__ int len_sh;

    const int tid = threadIdx.x;
    const bool isCol = tid < GATES;
    const int colid = isCol ? tid : (GATES - 1);

    for (int i = tid; i < T_LEN; i += 512)
        m_sh[i] = (unsigned char)(words[(size_t)b * T_LEN + i] != 0);
    if (tid < 52) reinterpret_cast<unsigned*>(h_sh)[tid] = 0u;   // all 104 f16

    unsigned upk[NQ];
#pragma unroll
    for (int q = 0; q < NQ; ++q) upk[q] = up[q * GATES + colid];
#pragma unroll
    for (int q = 0; q < NQ; ++q) asm volatile("" : "+v"(upk[q]));

    float c = 0.f, h = 0.f;
    __syncthreads();

    // len = first masked index; verify mask is a suffix, else disable skipping.
    if (tid == 0) {
        int fmi = T_LEN;
        for (int t = 0; t < T_LEN; ++t) if (!m_sh[t]) { fmi = t; break; }
        int ok = 1;
        for (int t = fmi; t < T_LEN; ++t) if (m_sh[t]) { ok = 0; break; }
        len_sh = ok ? fmi : T_LEN;
    }
    __syncthreads();
    const int len = len_sh;

    const short* xs = reinterpret_cast<const short*>(xw);

    // bwd: tail outputs are the initial h = 0 (masked steps carry state 0).
    if (dirv && tid < UNITS) {
        for (int t = len; t < T_LEN; ++t)
            hout[((size_t)t * B_SZ + b) * UNITS + tid] = (_Float16)0.f;
    }

    short pf = 0;
    if (isCol && len > 0) {
        const int tfirst = dirv ? (len - 1) : 0;
        pf = xs[((size_t)tfirst * B_SZ + b) * NCOL + coff + tid];
    }

    for (int s = 0; s < len; ++s) {
        const int t = dirv ? (len - 1 - s) : s;
        int tn = dirv ? (t - 1) : (t + 1);
        tn = tn < 0 ? 0 : (tn > T_LEN - 1 ? T_LEN - 1 : tn);

        short pfn = pf;
        if (isCol) {
            const float zx = bf2f(pf);
            pfn = xs[((size_t)tn * B_SZ + b) * NCOL + coff + tid];   // prefetch
            float a0 = 0.f, a1 = 0.f, a2 = 0.f, a3 = 0.f;
            const uint4* h4 = reinterpret_cast<const uint4*>(h_sh);
#pragma unroll
            for (int qq = 0; qq < 13; ++qq) {
                const uint4 hv = h4[qq];
                a0 = fdot2p(hv.x, upk[4 * qq + 0], a0);
                a1 = fdot2p(hv.y, upk[4 * qq + 1], a1);
                a2 = fdot2p(hv.z, upk[4 * qq + 2], a2);
                a3 = fdot2p(hv.w, upk[4 * qq + 3], a3);
            }
            z_sh[tid] = zx + (a0 + a1) + (a2 + a3);
        }
        pf = pfn;

        BAR();

        if (tid < UNITS) {
            const float zi = z_sh[tid];
            const float zf = z_sh[tid + UNITS];
            const float zg = z_sh[tid + 2 * UNITS];
            const float zo = z_sh[tid + 3 * UNITS];
            const float ig = fast_sigmoid(zi);
            const float fg = fast_sigmoid(zf);
            const float gg = fast_tanh(zg);
            const float og = fast_sigmoid(zo);
            const float cn = fg * c + ig * gg;
            const float hn = og * fast_tanh(cn);
            const bool  m  = m_sh[t] != 0;
            h = m ? hn : h;
            c = m ? cn : c;
            const _Float16 hh = (_Float16)h;
            h_sh[tid] = hh;
            hout[((size_t)t * B_SZ + b) * UNITS + tid] = hh;
        }

        BAR();
    }

    // fwd: tail outputs carry the final h (masked steps are identity).
    if (!dirv && tid < UNITS) {
        const _Float16 hh = (_Float16)h;
        for (int t = len; t < T_LEN; ++t)
            hout[((size_t)t * B_SZ + b) * UNITS + tid] = hh;
    }
}

// ---------------------------------------------------------------------------
// out_proj: out[b][t] = sigmoid(h_f . Wo[0:100] + h_b . Wo[100:200] + bo)
// ---------------------------------------------------------------------------
__global__ __launch_bounds__(256) void out_proj(
    const _Float16* __restrict__ h_f, const _Float16* __restrict__ h_b,
    const float* __restrict__ Wo, const float* __restrict__ bo,
    float* __restrict__ out)
{
    const int tid = threadIdx.x;
    const int g = tid >> 2, sub = tid & 3;
    const int r = blockIdx.x * 64 + g;      // r = t*256 + b
    const int t = r >> 8, b = r & 255;

    const _Float16* hf = h_f + (size_t)r * UNITS;
    const _Float16* hb = h_b + (size_t)r * UNITS;

    float s = 0.f;
    const int k0 = sub * 25;
#pragma unroll
    for (int k = 0; k < 25; ++k) s = fmaf((float)hf[k0 + k], Wo[k0 + k], s);
#pragma unroll
    for (int k = 0; k < 25; ++k) s = fmaf((float)hb[k0 + k], Wo[UNITS + k0 + k], s);

    s += __shfl_xor(s, 1);
    s += __shfl_xor(s, 2);

    if (sub == 0)
        out[(size_t)b * T_LEN + t] = 1.f / (1.f + __expf(-(s + bo[0])));
}

// ---------------------------------------------------------------------------
extern "C" void kernel_launch(void* const* d_in, const int* in_sizes, int n_in,
                              void* d_out, int out_size, void* d_ws, size_t ws_size,
                              hipStream_t stream)
{
    const int*   words = (const int*)d_in[0];
    const int*   pos   = (const int*)d_in[1];
    const int*   dep   = (const int*)d_in[2];
    const float* Ew    = (const float*)d_in[3];
    const float* Ep    = (const float*)d_in[4];
    const float* Ed    = (const float*)d_in[5];
    const float* Wf    = (const float*)d_in[6];
    const float* Uf    = (const float*)d_in[7];
    const float* bf_   = (const float*)d_in[8];
    const float* Wb    = (const float*)d_in[9];
    const float* Ub    = (const float*)d_in[10];
    const float* bb_   = (const float*)d_in[11];
    const float* Wo    = (const float*)d_in[12];
    const float* bo    = (const float*)d_in[13];
    float* out = (float*)d_out;

    auto alignup = [](size_t x) { return (x + 255) & ~(size_t)255; };
    char* p = (char*)d_ws;
    __hip_bfloat16* xw = (__hip_bfloat16*)p;  p += alignup((size_t)T_LEN * B_SZ * NCOL * 2);
    _Float16* h_f = (_Float16*)p;             p += alignup((size_t)T_LEN * B_SZ * UNITS * 2);
    _Float16* h_b = (_Float16*)p;             p += alignup((size_t)T_LEN * B_SZ * UNITS * 2);
    __hip_bfloat16* WbT = (__hip_bfloat16*)p; p += alignup((size_t)NCOL * 128 * 2);
    float* Ppos = (float*)p;                  p += alignup((size_t)53 * NCOL * 4);
    float* Pdep = (float*)p;                  p += alignup((size_t)54 * NCOL * 4);
    unsigned* Upk = (unsigned*)p;             p += alignup((size_t)2 * NQ * GATES * 4);
    int* flag = (int*)p;

    prep<<<dim3(PREP_WT_BLOCKS + PREP_TAB_BLOCKS + PREP_UPK_BLOCKS + 1), 256, 0, stream>>>(
        Wf, Wb, bf_, bb_, Ep, Ed, Uf, Ub, WbT, Ppos, Pdep, Upk, flag);

    embed_gemm<<<dim3((T_LEN * B_SZ) / MT, NCOL / NT), 256, 0, stream>>>(
        words, pos, dep, Ew, WbT, Ppos, Pdep, flag, xw);

    lstm_valu<<<dim3(B_SZ * 2), 512, 0, stream>>>(words, xw, Upk, h_f, h_b);

    out_proj<<<dim3((T_LEN * B_SZ) / 64), 256, 0, stream>>>(h_f, h_b, Wo, bo, out);
}